// Round 1
// baseline (9416.821 us; speedup 1.0000x reference)
//
#include <hip/hip_runtime.h>
#include <cstdint>
#include <cstddef>

#define HD 128
#define NLAYER 4
#define EINDIM 385

__device__ __forceinline__ float silu_f(float x) {
    return x / (1.f + __expf(-x));
}

// ---------------- init: lam_vec + folded edge bias c1 ----------------
__global__ void k_init(const float* __restrict__ lam_p,
                       const float* __restrict__ lam_w,
                       const float* __restrict__ lam_b,
                       const float* __restrict__ edge_w1,
                       const float* __restrict__ edge_b1,
                       float* __restrict__ lam_vec,
                       float* __restrict__ c1) {
    __shared__ float sl[HD];
    int tid = threadIdx.x;
    float lam = lam_p[0];
    if (tid < HD) {
        float v = lam * lam_w[tid] + lam_b[tid];
        lam_vec[tid] = v;
        sl[tid] = v;
    }
    __syncthreads();
    for (int idx = tid; idx < NLAYER * HD; idx += 256) {
        int l = idx >> 7, j = idx & 127;
        float acc = edge_b1[l * HD + j];
        const float* w = edge_w1 + ((size_t)l * EINDIM + 257) * HD + j;
        for (int k = 0; k < HD; k++) acc = fmaf(sl[k], w[(size_t)k * HD], acc);
        c1[idx] = acc;
    }
}

// ---------------- h0 = atom_embed[z] + lam_vec ----------------
__global__ void k_embed(const int* __restrict__ z,
                        const float* __restrict__ atom_embed,
                        const float* __restrict__ lam_vec,
                        float* __restrict__ h, int n4) {
    int i = blockIdx.x * 256 + threadIdx.x;
    if (i >= n4) return;
    int n = i >> 5, q = i & 31;
    int a = z[n];
    float4 e = *(const float4*)&atom_embed[(size_t)a * HD + q * 4];
    float4 lv = *(const float4*)&lam_vec[q * 4];
    e.x += lv.x; e.y += lv.y; e.z += lv.z; e.w += lv.w;
    *(float4*)&h[(size_t)n * HD + q * 4] = e;
}

// ---------------- dist per edge ----------------
__global__ void k_dist(const float* __restrict__ pos,
                       const int* __restrict__ ei,
                       float* __restrict__ dist, int E) {
    int e = blockIdx.x * 256 + threadIdx.x;
    if (e >= E) return;
    int r = ei[e], c = ei[E + e];
    float dx = pos[r * 3 + 0] - pos[c * 3 + 0];
    float dy = pos[r * 3 + 1] - pos[c * 3 + 1];
    float dz = pos[r * 3 + 2] - pos[c * 3 + 2];
    dist[e] = sqrtf(dx * dx + dy * dy + dz * dz + 1e-8f);
}

// ---------------- edge MLP (2 layers) + atomic scatter into agg ----------------
// tile: 64 edges x 128 out, K=256 (h_row||h_col), dist folded as rank-1, lam folded in c1
__global__ __launch_bounds__(256, 2) void k_edge(
    const float* __restrict__ h, const float* __restrict__ dist,
    const int* __restrict__ ei, int E,
    const float* __restrict__ w1,   // layer base: 385x128 (rows 0..255 used here)
    const float* __restrict__ w2,   // 128x128
    const float* __restrict__ c1,   // 128 folded bias
    const float* __restrict__ b2,   // 128
    float* __restrict__ agg) {
    __shared__ float shA[64 * 260];      // A tile (stride 260); reused as M tile (stride 132)
    __shared__ float shB[16 * HD];
    __shared__ int shRow[64];
    __shared__ int shCol[64];
    __shared__ float shD[64];
    __shared__ float shWd[HD], shC1[HD], shB2[HD];

    const int tid = threadIdx.x;
    const int e0 = blockIdx.x * 64;

    if (tid < 64) {
        int e = e0 + tid;
        shRow[tid] = (e < E) ? ei[e] : 0;
        shCol[tid] = (e < E) ? ei[E + e] : 0;
        shD[tid]   = (e < E) ? dist[e] : 0.f;
    }
    if (tid >= 128) {
        int j = tid - 128;
        shWd[j] = w1[256 * HD + j];
        shC1[j] = c1[j];
        shB2[j] = b2[j];
    }
    __syncthreads();

    // stage A: 64 edges x 256 floats (h[row] || h[col])
#pragma unroll
    for (int i = 0; i < 16; i++) {
        int flat = tid + i * 256;       // float4 index
        int e = flat >> 6;
        int f4 = flat & 63;
        const float* src = (f4 < 32) ? (h + (size_t)shRow[e] * HD + f4 * 4)
                                     : (h + (size_t)shCol[e] * HD + (f4 - 32) * 4);
        float4 v = *(const float4*)src;
        *(float4*)&shA[e * 260 + f4 * 4] = v;
    }

    const int ty = tid >> 4;   // 0..15 -> edges ty*4 .. ty*4+3
    const int tx = tid & 15;   // cols tx*8 .. tx*8+7

    float acc[4][8];
#pragma unroll
    for (int r = 0; r < 4; r++)
#pragma unroll
        for (int c = 0; c < 8; c++) acc[r][c] = 0.f;

    for (int k0 = 0; k0 < 256; k0 += 16) {
        __syncthreads();
#pragma unroll
        for (int i = 0; i < 2; i++) {
            int flat = tid + i * 256;
            int kk = flat >> 5, j4 = flat & 31;
            *(float4*)&shB[kk * HD + j4 * 4] =
                *(const float4*)&w1[(size_t)(k0 + kk) * HD + j4 * 4];
        }
        __syncthreads();
#pragma unroll
        for (int kk = 0; kk < 16; kk++) {
            float a0 = shA[(ty * 4 + 0) * 260 + k0 + kk];
            float a1 = shA[(ty * 4 + 1) * 260 + k0 + kk];
            float a2 = shA[(ty * 4 + 2) * 260 + k0 + kk];
            float a3 = shA[(ty * 4 + 3) * 260 + k0 + kk];
            float4 bA = *(float4*)&shB[kk * HD + tx * 8];
            float4 bB = *(float4*)&shB[kk * HD + tx * 8 + 4];
            float bb[8] = {bA.x, bA.y, bA.z, bA.w, bB.x, bB.y, bB.z, bB.w};
#pragma unroll
            for (int c = 0; c < 8; c++) {
                acc[0][c] = fmaf(a0, bb[c], acc[0][c]);
                acc[1][c] = fmaf(a1, bb[c], acc[1][c]);
                acc[2][c] = fmaf(a2, bb[c], acc[2][c]);
                acc[3][c] = fmaf(a3, bb[c], acc[3][c]);
            }
        }
    }
    __syncthreads();
    // m = silu(acc + dist*wd + c1) -> shA reused as 64x132
#pragma unroll
    for (int r = 0; r < 4; r++) {
        float d = shD[ty * 4 + r];
#pragma unroll
        for (int c = 0; c < 8; c++) {
            int j = tx * 8 + c;
            float x = acc[r][c] + d * shWd[j] + shC1[j];
            shA[(ty * 4 + r) * 132 + j] = silu_f(x);
        }
    }

    float acc2[4][8];
#pragma unroll
    for (int r = 0; r < 4; r++)
#pragma unroll
        for (int c = 0; c < 8; c++) acc2[r][c] = 0.f;

    for (int k0 = 0; k0 < 128; k0 += 16) {
        __syncthreads();
#pragma unroll
        for (int i = 0; i < 2; i++) {
            int flat = tid + i * 256;
            int kk = flat >> 5, j4 = flat & 31;
            *(float4*)&shB[kk * HD + j4 * 4] =
                *(const float4*)&w2[(size_t)(k0 + kk) * HD + j4 * 4];
        }
        __syncthreads();
#pragma unroll
        for (int kk = 0; kk < 16; kk++) {
            float a0 = shA[(ty * 4 + 0) * 132 + k0 + kk];
            float a1 = shA[(ty * 4 + 1) * 132 + k0 + kk];
            float a2 = shA[(ty * 4 + 2) * 132 + k0 + kk];
            float a3 = shA[(ty * 4 + 3) * 132 + k0 + kk];
            float4 bA = *(float4*)&shB[kk * HD + tx * 8];
            float4 bB = *(float4*)&shB[kk * HD + tx * 8 + 4];
            float bb[8] = {bA.x, bA.y, bA.z, bA.w, bB.x, bB.y, bB.z, bB.w};
#pragma unroll
            for (int c = 0; c < 8; c++) {
                acc2[0][c] = fmaf(a0, bb[c], acc2[0][c]);
                acc2[1][c] = fmaf(a1, bb[c], acc2[1][c]);
                acc2[2][c] = fmaf(a2, bb[c], acc2[2][c]);
                acc2[3][c] = fmaf(a3, bb[c], acc2[3][c]);
            }
        }
    }
    // epilogue: silu + scatter
#pragma unroll
    for (int r = 0; r < 4; r++) {
        int e = e0 + ty * 4 + r;
        if (e < E) {
            float* dst = agg + (size_t)shRow[ty * 4 + r] * HD;
#pragma unroll
            for (int c = 0; c < 8; c++) {
                int j = tx * 8 + c;
                atomicAdd(dst + j, silu_f(acc2[r][c] + shB2[j]));
            }
        }
    }
}

// ---------------- node MLP (2 layers), writes u ----------------
__global__ __launch_bounds__(256, 2) void k_node(
    const float* __restrict__ h, const float* __restrict__ agg, int N,
    const float* __restrict__ w1,   // 256x128
    const float* __restrict__ w2,   // 128x128
    const float* __restrict__ b1, const float* __restrict__ b2,
    float* __restrict__ u) {
    __shared__ float shA[64 * 260];
    __shared__ float shB[16 * HD];
    __shared__ float shB1[HD], shB2[HD];

    const int tid = threadIdx.x;
    const int n0 = blockIdx.x * 64;
    if (tid < 128) { shB1[tid] = b1[tid]; shB2[tid] = b2[tid]; }

#pragma unroll
    for (int i = 0; i < 16; i++) {
        int flat = tid + i * 256;
        int e = flat >> 6, f4 = flat & 63;
        int n = n0 + e;
        float4 v = {0.f, 0.f, 0.f, 0.f};
        if (n < N) {
            v = (f4 < 32) ? *(const float4*)&h[(size_t)n * HD + f4 * 4]
                          : *(const float4*)&agg[(size_t)n * HD + (f4 - 32) * 4];
        }
        *(float4*)&shA[e * 260 + f4 * 4] = v;
    }

    const int ty = tid >> 4;
    const int tx = tid & 15;

    float acc[4][8];
#pragma unroll
    for (int r = 0; r < 4; r++)
#pragma unroll
        for (int c = 0; c < 8; c++) acc[r][c] = 0.f;

    for (int k0 = 0; k0 < 256; k0 += 16) {
        __syncthreads();
#pragma unroll
        for (int i = 0; i < 2; i++) {
            int flat = tid + i * 256;
            int kk = flat >> 5, j4 = flat & 31;
            *(float4*)&shB[kk * HD + j4 * 4] =
                *(const float4*)&w1[(size_t)(k0 + kk) * HD + j4 * 4];
        }
        __syncthreads();
#pragma unroll
        for (int kk = 0; kk < 16; kk++) {
            float a0 = shA[(ty * 4 + 0) * 260 + k0 + kk];
            float a1 = shA[(ty * 4 + 1) * 260 + k0 + kk];
            float a2 = shA[(ty * 4 + 2) * 260 + k0 + kk];
            float a3 = shA[(ty * 4 + 3) * 260 + k0 + kk];
            float4 bA = *(float4*)&shB[kk * HD + tx * 8];
            float4 bB = *(float4*)&shB[kk * HD + tx * 8 + 4];
            float bb[8] = {bA.x, bA.y, bA.z, bA.w, bB.x, bB.y, bB.z, bB.w};
#pragma unroll
            for (int c = 0; c < 8; c++) {
                acc[0][c] = fmaf(a0, bb[c], acc[0][c]);
                acc[1][c] = fmaf(a1, bb[c], acc[1][c]);
                acc[2][c] = fmaf(a2, bb[c], acc[2][c]);
                acc[3][c] = fmaf(a3, bb[c], acc[3][c]);
            }
        }
    }
    __syncthreads();
#pragma unroll
    for (int r = 0; r < 4; r++) {
#pragma unroll
        for (int c = 0; c < 8; c++) {
            int j = tx * 8 + c;
            shA[(ty * 4 + r) * 132 + j] = silu_f(acc[r][c] + shB1[j]);
        }
    }

    float acc2[4][8];
#pragma unroll
    for (int r = 0; r < 4; r++)
#pragma unroll
        for (int c = 0; c < 8; c++) acc2[r][c] = 0.f;

    for (int k0 = 0; k0 < 128; k0 += 16) {
        __syncthreads();
#pragma unroll
        for (int i = 0; i < 2; i++) {
            int flat = tid + i * 256;
            int kk = flat >> 5, j4 = flat & 31;
            *(float4*)&shB[kk * HD + j4 * 4] =
                *(const float4*)&w2[(size_t)(k0 + kk) * HD + j4 * 4];
        }
        __syncthreads();
#pragma unroll
        for (int kk = 0; kk < 16; kk++) {
            float a0 = shA[(ty * 4 + 0) * 132 + k0 + kk];
            float a1 = shA[(ty * 4 + 1) * 132 + k0 + kk];
            float a2 = shA[(ty * 4 + 2) * 132 + k0 + kk];
            float a3 = shA[(ty * 4 + 3) * 132 + k0 + kk];
            float4 bA = *(float4*)&shB[kk * HD + tx * 8];
            float4 bB = *(float4*)&shB[kk * HD + tx * 8 + 4];
            float bb[8] = {bA.x, bA.y, bA.z, bA.w, bB.x, bB.y, bB.z, bB.w};
#pragma unroll
            for (int c = 0; c < 8; c++) {
                acc2[0][c] = fmaf(a0, bb[c], acc2[0][c]);
                acc2[1][c] = fmaf(a1, bb[c], acc2[1][c]);
                acc2[2][c] = fmaf(a2, bb[c], acc2[2][c]);
                acc2[3][c] = fmaf(a3, bb[c], acc2[3][c]);
            }
        }
    }
    // write u = acc2 + b2 (no silu)
#pragma unroll
    for (int r = 0; r < 4; r++) {
        int n = n0 + ty * 4 + r;
        if (n < N) {
#pragma unroll
            for (int c = 0; c < 8; c += 4) {
                float4 v;
                v.x = acc2[r][c + 0] + shB2[tx * 8 + c + 0];
                v.y = acc2[r][c + 1] + shB2[tx * 8 + c + 1];
                v.z = acc2[r][c + 2] + shB2[tx * 8 + c + 2];
                v.w = acc2[r][c + 3] + shB2[tx * 8 + c + 3];
                *(float4*)&u[(size_t)n * HD + tx * 8 + c] = v;
            }
        }
    }
}

// ---------------- h = LN(h + u), wave per row ----------------
__global__ __launch_bounds__(256) void k_ln(const float* __restrict__ u,
                                            float* __restrict__ h,
                                            const float* __restrict__ g,
                                            const float* __restrict__ b, int N) {
    int w = threadIdx.x >> 6, lane = threadIdx.x & 63;
    int row = blockIdx.x * 4 + w;
    if (row >= N) return;
    float2 h2 = *(const float2*)&h[(size_t)row * HD + lane * 2];
    float2 u2 = *(const float2*)&u[(size_t)row * HD + lane * 2];
    float x0 = h2.x + u2.x, x1 = h2.y + u2.y;
    float s = x0 + x1, ss = x0 * x0 + x1 * x1;
#pragma unroll
    for (int o = 32; o > 0; o >>= 1) {
        s += __shfl_xor(s, o);
        ss += __shfl_xor(ss, o);
    }
    float mean = s * (1.f / 128.f);
    float var = ss * (1.f / 128.f) - mean * mean;
    float rstd = rsqrtf(var + 1e-5f);
    float2 o2;
    o2.x = (x0 - mean) * rstd * g[lane * 2] + b[lane * 2];
    o2.y = (x1 - mean) * rstd * g[lane * 2 + 1] + b[lane * 2 + 1];
    *(float2*)&h[(size_t)row * HD + lane * 2] = o2;
}

// ---------------- pooling stage 1: per-block partial sums ----------------
__global__ __launch_bounds__(256) void k_pool1(const float* __restrict__ h,
                                               float* __restrict__ partial,
                                               int N, int RPB) {
    int bk = blockIdx.x, t = threadIdx.x;
    int j = t & 127, half = t >> 7;
    float s = 0.f;
    int rend = (bk + 1) * RPB; if (rend > N) rend = N;
    for (int r = bk * RPB + half; r < rend; r += 2) s += h[(size_t)r * HD + j];
    __shared__ float sh[256];
    sh[t] = s;
    __syncthreads();
    if (t < 128) partial[bk * HD + j] = sh[t] + sh[t + 128];
}

// ---------------- pooling stage 2 + head MLP ----------------
__global__ __launch_bounds__(128) void k_head(const float* __restrict__ partial,
                                              int nPart, int N,
                                              const float* __restrict__ hw1,
                                              const float* __restrict__ hb1,
                                              const float* __restrict__ hw2,
                                              const float* __restrict__ hb2,
                                              float* __restrict__ out) {
    __shared__ float pooled[HD];
    __shared__ float t1[HD];
    int j = threadIdx.x;
    double s = 0.0;
    for (int bk = 0; bk < nPart; bk++) s += (double)partial[bk * HD + j];
    pooled[j] = (float)(s / (double)N);
    __syncthreads();
    float acc = hb1[j];
    for (int k = 0; k < HD; k++) acc = fmaf(pooled[k], hw1[k * HD + j], acc);
    t1[j] = silu_f(acc) * hw2[j];
    __syncthreads();
    if (j < 64) t1[j] += t1[j + 64];
    __syncthreads();
    if (j < 64) {
        float v = t1[j];
#pragma unroll
        for (int o = 32; o > 0; o >>= 1) v += __shfl_xor(v, o);
        if (j == 0) out[0] = v + hb2[0];
    }
}

extern "C" void kernel_launch(void* const* d_in, const int* in_sizes, int n_in,
                              void* d_out, int out_size, void* d_ws, size_t ws_size,
                              hipStream_t stream) {
    const int* z      = (const int*)d_in[0];
    const float* pos  = (const float*)d_in[1];
    const int* ei     = (const int*)d_in[2];
    const float* lam  = (const float*)d_in[3];
    const float* aemb = (const float*)d_in[4];
    const float* lamw = (const float*)d_in[5];
    const float* lamb = (const float*)d_in[6];
    const float* ew1  = (const float*)d_in[7];
    const float* eb1  = (const float*)d_in[8];
    const float* ew2  = (const float*)d_in[9];
    const float* eb2  = (const float*)d_in[10];
    const float* nw1  = (const float*)d_in[11];
    const float* nb1  = (const float*)d_in[12];
    const float* nw2  = (const float*)d_in[13];
    const float* nb2  = (const float*)d_in[14];
    const float* lng  = (const float*)d_in[15];
    const float* lnb  = (const float*)d_in[16];
    const float* hw1  = (const float*)d_in[17];
    const float* hb1  = (const float*)d_in[18];
    const float* hw2  = (const float*)d_in[19];
    const float* hb2  = (const float*)d_in[20];

    const int N = in_sizes[0];
    const int E = in_sizes[2] / 2;

    float* ws = (float*)d_ws;
    size_t off = 0;
    float* h    = ws + off; off += (size_t)N * HD;
    float* agg  = ws + off; off += (size_t)N * HD;
    float* u    = ws + off; off += (size_t)N * HD;
    float* dist = ws + off; off += (size_t)E;
    float* lamv = ws + off; off += HD;
    float* c1   = ws + off; off += NLAYER * HD;
    float* part = ws + off; off += 256 * HD;

    k_init<<<1, 256, 0, stream>>>(lam, lamw, lamb, ew1, eb1, lamv, c1);
    int n4 = N * 32;
    k_embed<<<(n4 + 255) / 256, 256, 0, stream>>>(z, aemb, lamv, h, n4);
    k_dist<<<(E + 255) / 256, 256, 0, stream>>>(pos, ei, dist, E);

    int eblocks = (E + 63) / 64;
    int nblocks = (N + 63) / 64;
    for (int l = 0; l < NLAYER; l++) {
        hipMemsetAsync(agg, 0, (size_t)N * HD * sizeof(float), stream);
        k_edge<<<eblocks, 256, 0, stream>>>(h, dist, ei, E,
            ew1 + (size_t)l * EINDIM * HD, ew2 + (size_t)l * HD * HD,
            c1 + l * HD, eb2 + l * HD, agg);
        k_node<<<nblocks, 256, 0, stream>>>(h, agg, N,
            nw1 + (size_t)l * 2 * HD * HD, nw2 + (size_t)l * HD * HD,
            nb1 + l * HD, nb2 + l * HD, u);
        k_ln<<<(N + 3) / 4, 256, 0, stream>>>(u, h, lng + l * HD, lnb + l * HD, N);
    }
    int RPB = (N + 255) / 256;
    k_pool1<<<256, 256, 0, stream>>>(h, part, N, RPB);
    k_head<<<1, 128, 0, stream>>>(part, 256, N, hw1, hb1, hw2, hb2, (float*)d_out);
}

// Round 2
// 1631.934 us; speedup vs baseline: 5.7703x; 5.7703x over previous
//
#include <hip/hip_runtime.h>
#include <cstdint>
#include <cstddef>

#define HD 128
#define NLAYER 4
#define EINDIM 385

typedef _Float16 f16x8 __attribute__((ext_vector_type(8)));
typedef _Float16 f16x4 __attribute__((ext_vector_type(4)));
typedef float f32x4 __attribute__((ext_vector_type(4)));

__device__ __forceinline__ float silu_f(float x) {
    return x / (1.f + __expf(-x));
}

// ---------------- init: lam_vec + folded edge bias c1 (fp32) ----------------
__global__ void k_init(const float* __restrict__ lam_p,
                       const float* __restrict__ lam_w,
                       const float* __restrict__ lam_b,
                       const float* __restrict__ edge_w1,
                       const float* __restrict__ edge_b1,
                       float* __restrict__ lam_vec,
                       float* __restrict__ c1) {
    __shared__ float sl[HD];
    int tid = threadIdx.x;
    float lam = lam_p[0];
    if (tid < HD) {
        float v = lam * lam_w[tid] + lam_b[tid];
        lam_vec[tid] = v;
        sl[tid] = v;
    }
    __syncthreads();
    for (int idx = tid; idx < NLAYER * HD; idx += 256) {
        int l = idx >> 7, j = idx & 127;
        float acc = edge_b1[l * HD + j];
        const float* w = edge_w1 + ((size_t)l * EINDIM + 257) * HD + j;
        for (int k = 0; k < HD; k++) acc = fmaf(sl[k], w[(size_t)k * HD], acc);
        c1[idx] = acc;
    }
}

// ---------------- prep: transpose weights to [col][k] fp16, extract dist row ----------------
__global__ void k_prep(const float* __restrict__ ew1, const float* __restrict__ ew2,
                       const float* __restrict__ nw1, const float* __restrict__ nw2,
                       _Float16* __restrict__ W1te, _Float16* __restrict__ W2te,
                       _Float16* __restrict__ W1tn, _Float16* __restrict__ W2tn,
                       float* __restrict__ wd) {
    int t = blockIdx.x * 256 + threadIdx.x;
    if (t < NLAYER * 128 * 256) {
        int l = t >> 15, r = t & 32767, j = r >> 8, k = r & 255;
        W1te[t] = (_Float16)ew1[((size_t)l * EINDIM + k) * HD + j];
        return;
    }
    t -= NLAYER * 128 * 256;
    if (t < NLAYER * 128 * 256) {
        int l = t >> 15, r = t & 32767, j = r >> 8, k = r & 255;
        W1tn[t] = (_Float16)nw1[((size_t)l * 256 + k) * HD + j];
        return;
    }
    t -= NLAYER * 128 * 256;
    if (t < NLAYER * 128 * 128) {
        int l = t >> 14, r = t & 16383, j = r >> 7, k = r & 127;
        W2te[t] = (_Float16)ew2[((size_t)l * 128 + k) * HD + j];
        return;
    }
    t -= NLAYER * 128 * 128;
    if (t < NLAYER * 128 * 128) {
        int l = t >> 14, r = t & 16383, j = r >> 7, k = r & 127;
        W2tn[t] = (_Float16)nw2[((size_t)l * 128 + k) * HD + j];
        return;
    }
    t -= NLAYER * 128 * 128;
    if (t < NLAYER * 128) {
        int l = t >> 7, j = t & 127;
        wd[t] = ew1[((size_t)l * EINDIM + 256) * HD + j];
    }
}

// ---------------- h0 = atom_embed[z] + lam_vec (fp32 + fp16 copies) ----------------
__global__ void k_embed(const int* __restrict__ z,
                        const float* __restrict__ atom_embed,
                        const float* __restrict__ lam_vec,
                        float* __restrict__ h, _Float16* __restrict__ hh, int n4) {
    int i = blockIdx.x * 256 + threadIdx.x;
    if (i >= n4) return;
    int n = i >> 5, q = i & 31;
    int a = z[n];
    float4 e = *(const float4*)&atom_embed[(size_t)a * HD + q * 4];
    float4 lv = *(const float4*)&lam_vec[q * 4];
    e.x += lv.x; e.y += lv.y; e.z += lv.z; e.w += lv.w;
    *(float4*)&h[(size_t)n * HD + q * 4] = e;
    f16x4 hv;
    hv[0] = (_Float16)e.x; hv[1] = (_Float16)e.y;
    hv[2] = (_Float16)e.z; hv[3] = (_Float16)e.w;
    *(f16x4*)&hh[(size_t)n * HD + q * 4] = hv;
}

// ---------------- dist per edge ----------------
__global__ void k_dist(const float* __restrict__ pos,
                       const int* __restrict__ ei,
                       float* __restrict__ dist, int E) {
    int e = blockIdx.x * 256 + threadIdx.x;
    if (e >= E) return;
    int r = ei[e], c = ei[E + e];
    float dx = pos[r * 3 + 0] - pos[c * 3 + 0];
    float dy = pos[r * 3 + 1] - pos[c * 3 + 1];
    float dz = pos[r * 3 + 2] - pos[c * 3 + 2];
    dist[e] = sqrtf(dx * dx + dy * dy + dz * dz + 1e-8f);
}

// ---------------- zero agg ----------------
__global__ void k_zero(float4* __restrict__ p, int n4) {
    for (int i = blockIdx.x * 256 + threadIdx.x; i < n4; i += gridDim.x * 256)
        p[i] = make_float4(0.f, 0.f, 0.f, 0.f);
}

// =======================================================================
// edge MLP via MFMA fp16: tile 64 edges x 128 out.
// 4 waves, wave w owns rows w*16..w*16+15 (all 128 cols, 8 col-frags).
// GEMM1: K=256 (h_row||h_col); dist folded as rank-1 fp32; lam folded in c1.
// A frag: lane l -> A[l&15][k0+(l>>4)*8 ..+8]; B frag: W^T[col=f*16+(l&15)][same k]
// D: row=(l>>4)*4+r, col=l&15  (verified layout, learn_hip m89/m91)
// =======================================================================
__global__ __launch_bounds__(256, 3) void k_edge_mfma(
    const _Float16* __restrict__ hh, const float* __restrict__ dist,
    const int* __restrict__ ei, int E,
    const _Float16* __restrict__ W1t,   // [128][256]
    const _Float16* __restrict__ W2t,   // [128][128]
    const float* __restrict__ wd, const float* __restrict__ c1,
    const float* __restrict__ b2,
    float* __restrict__ agg) {
    __shared__ __align__(16) _Float16 shA[64 * 264];   // A tile; reused as M tile [64][136]
    __shared__ __align__(16) _Float16 shB[128 * 40];   // one K=32 weight slab, [col][k] padded
    __shared__ int shRow[64], shCol[64];
    __shared__ float shD[64], shWd[HD], shC1[HD], shB2[HD];

    const int tid = threadIdx.x;
    const int e0 = blockIdx.x * 64;
    const int w = tid >> 6, l = tid & 63;
    const int lg = l >> 4, lr = l & 15;

    if (tid < 64) {
        int e = e0 + tid;
        shRow[tid] = (e < E) ? ei[e] : 0;
        shCol[tid] = (e < E) ? ei[E + e] : 0;
        shD[tid]   = (e < E) ? dist[e] : 0.f;
    }
    if (tid >= 128) {
        int j = tid - 128;
        shWd[j] = wd[j]; shC1[j] = c1[j]; shB2[j] = b2[j];
    }
    __syncthreads();

    // stage A: 64 edges x (h[row]||h[col]) fp16, 16B chunks
#pragma unroll
    for (int it = 0; it < 8; it++) {
        int flat = tid + it * 256;
        int e = flat >> 5, c = flat & 31;
        const _Float16* src = (c < 16) ? hh + (size_t)shRow[e] * HD + c * 8
                                       : hh + (size_t)shCol[e] * HD + (c - 16) * 8;
        *(f16x8*)&shA[e * 264 + c * 8] = *(const f16x8*)src;
    }

    f32x4 acc[8];
#pragma unroll
    for (int f = 0; f < 8; f++) acc[f] = (f32x4){0.f, 0.f, 0.f, 0.f};

    // GEMM1: K=256, 8 steps of 32
    for (int k0 = 0; k0 < 256; k0 += 32) {
        __syncthreads();
#pragma unroll
        for (int p = 0; p < 2; p++) {
            int flat = tid + p * 256;
            int j = flat >> 2, q = flat & 3;
            *(f16x8*)&shB[j * 40 + q * 8] =
                *(const f16x8*)(W1t + (size_t)j * 256 + k0 + q * 8);
        }
        __syncthreads();
        f16x8 a = *(const f16x8*)&shA[(w * 16 + lr) * 264 + k0 + lg * 8];
#pragma unroll
        for (int f = 0; f < 8; f++) {
            f16x8 b = *(const f16x8*)&shB[(f * 16 + lr) * 40 + lg * 8];
            acc[f] = __builtin_amdgcn_mfma_f32_16x16x32_f16(a, b, acc[f], 0, 0, 0);
        }
    }
    __syncthreads();   // shA reads done everywhere before reuse as M

    // epilogue1: m = silu(acc + dist*wd + c1) -> shM (fp16), [64][136]
    _Float16* shM = shA;
#pragma unroll
    for (int f = 0; f < 8; f++) {
#pragma unroll
        for (int r = 0; r < 4; r++) {
            int row = w * 16 + lg * 4 + r;
            int col = f * 16 + lr;
            float x = acc[f][r] + shD[row] * shWd[col] + shC1[col];
            shM[row * 136 + col] = (_Float16)silu_f(x);
        }
    }

    f32x4 acc2[8];
#pragma unroll
    for (int f = 0; f < 8; f++) acc2[f] = (f32x4){0.f, 0.f, 0.f, 0.f};

    // GEMM2: K=128, 4 steps of 32
    for (int k0 = 0; k0 < 128; k0 += 32) {
        __syncthreads();   // first iter: also covers shM writes
#pragma unroll
        for (int p = 0; p < 2; p++) {
            int flat = tid + p * 256;
            int j = flat >> 2, q = flat & 3;
            *(f16x8*)&shB[j * 40 + q * 8] =
                *(const f16x8*)(W2t + (size_t)j * 128 + k0 + q * 8);
        }
        __syncthreads();
        f16x8 a = *(const f16x8*)&shM[(w * 16 + lr) * 136 + k0 + lg * 8];
#pragma unroll
        for (int f = 0; f < 8; f++) {
            f16x8 b = *(const f16x8*)&shB[(f * 16 + lr) * 40 + lg * 8];
            acc2[f] = __builtin_amdgcn_mfma_f32_16x16x32_f16(a, b, acc2[f], 0, 0, 0);
        }
    }

    // epilogue2: silu + atomic scatter (E % 64 == 0 for this problem, but guard anyway)
#pragma unroll
    for (int f = 0; f < 8; f++) {
#pragma unroll
        for (int r = 0; r < 4; r++) {
            int row = w * 16 + lg * 4 + r;
            int col = f * 16 + lr;
            if (e0 + row < E) {
                float v = silu_f(acc2[f][r] + shB2[col]);
                atomicAdd(agg + (size_t)shRow[row] * HD + col, v);
            }
        }
    }
}

// =======================================================================
// node MLP via MFMA fp16 + fused residual + LayerNorm.
// A = [hh[n] | fp16(agg[n])], K=256; writes h (fp32) and hh (fp16) in place.
// =======================================================================
__global__ __launch_bounds__(256, 3) void k_node_mfma(
    const _Float16* __restrict__ hh_in, const float* __restrict__ agg, int N,
    const _Float16* __restrict__ W1t,   // [128][256]
    const _Float16* __restrict__ W2t,   // [128][128]
    const float* __restrict__ b1, const float* __restrict__ b2,
    const float* __restrict__ lng, const float* __restrict__ lnb,
    float* __restrict__ h, _Float16* __restrict__ hh_out) {
    __shared__ __align__(16) _Float16 shA[64 * 264];
    __shared__ __align__(16) _Float16 shB[128 * 40];
    __shared__ float shB1[HD], shB2[HD], shG[HD], shBt[HD];

    const int tid = threadIdx.x;
    const int n0 = blockIdx.x * 64;
    const int w = tid >> 6, l = tid & 63;
    const int lg = l >> 4, lr = l & 15;

    if (tid < 128) { shB1[tid] = b1[tid]; shB2[tid] = b2[tid]; }
    else { int j = tid - 128; shG[j] = lng[j]; shBt[j] = lnb[j]; }

#pragma unroll
    for (int it = 0; it < 8; it++) {
        int flat = tid + it * 256;
        int e = flat >> 5, c = flat & 31;
        int n = n0 + e;
        f16x8 v = {};
        if (n < N) {
            if (c < 16) {
                v = *(const f16x8*)(hh_in + (size_t)n * HD + c * 8);
            } else {
                const float* s = agg + (size_t)n * HD + (c - 16) * 8;
                float4 v0 = *(const float4*)s;
                float4 v1 = *(const float4*)(s + 4);
                v[0] = (_Float16)v0.x; v[1] = (_Float16)v0.y;
                v[2] = (_Float16)v0.z; v[3] = (_Float16)v0.w;
                v[4] = (_Float16)v1.x; v[5] = (_Float16)v1.y;
                v[6] = (_Float16)v1.z; v[7] = (_Float16)v1.w;
            }
        }
        *(f16x8*)&shA[e * 264 + c * 8] = v;
    }

    f32x4 acc[8];
#pragma unroll
    for (int f = 0; f < 8; f++) acc[f] = (f32x4){0.f, 0.f, 0.f, 0.f};

    for (int k0 = 0; k0 < 256; k0 += 32) {
        __syncthreads();
#pragma unroll
        for (int p = 0; p < 2; p++) {
            int flat = tid + p * 256;
            int j = flat >> 2, q = flat & 3;
            *(f16x8*)&shB[j * 40 + q * 8] =
                *(const f16x8*)(W1t + (size_t)j * 256 + k0 + q * 8);
        }
        __syncthreads();
        f16x8 a = *(const f16x8*)&shA[(w * 16 + lr) * 264 + k0 + lg * 8];
#pragma unroll
        for (int f = 0; f < 8; f++) {
            f16x8 b = *(const f16x8*)&shB[(f * 16 + lr) * 40 + lg * 8];
            acc[f] = __builtin_amdgcn_mfma_f32_16x16x32_f16(a, b, acc[f], 0, 0, 0);
        }
    }
    __syncthreads();

    _Float16* shM = shA;
#pragma unroll
    for (int f = 0; f < 8; f++) {
#pragma unroll
        for (int r = 0; r < 4; r++) {
            int row = w * 16 + lg * 4 + r;
            int col = f * 16 + lr;
            shM[row * 136 + col] = (_Float16)silu_f(acc[f][r] + shB1[col]);
        }
    }

    f32x4 acc2[8];
#pragma unroll
    for (int f = 0; f < 8; f++) acc2[f] = (f32x4){0.f, 0.f, 0.f, 0.f};

    for (int k0 = 0; k0 < 128; k0 += 32) {
        __syncthreads();
#pragma unroll
        for (int p = 0; p < 2; p++) {
            int flat = tid + p * 256;
            int j = flat >> 2, q = flat & 3;
            *(f16x8*)&shB[j * 40 + q * 8] =
                *(const f16x8*)(W2t + (size_t)j * 128 + k0 + q * 8);
        }
        __syncthreads();
        f16x8 a = *(const f16x8*)&shM[(w * 16 + lr) * 136 + k0 + lg * 8];
#pragma unroll
        for (int f = 0; f < 8; f++) {
            f16x8 b = *(const f16x8*)&shB[(f * 16 + lr) * 40 + lg * 8];
            acc2[f] = __builtin_amdgcn_mfma_f32_16x16x32_f16(a, b, acc2[f], 0, 0, 0);
        }
    }

    // fused residual + LayerNorm epilogue; row lives in 16 lanes (same lg group)
#pragma unroll
    for (int r = 0; r < 4; r++) {
        int row = w * 16 + lg * 4 + r;
        int n = n0 + row;
        // x = h + u (residual in fp32)
#pragma unroll
        for (int f = 0; f < 8; f++) {
            int col = f * 16 + lr;
            float hres = (n < N) ? h[(size_t)n * HD + col] : 0.f;
            acc2[f][r] = hres + acc2[f][r] + shB2[col];
        }
        float s = 0.f, ss = 0.f;
#pragma unroll
        for (int f = 0; f < 8; f++) { float v = acc2[f][r]; s += v; ss += v * v; }
#pragma unroll
        for (int m = 1; m < 16; m <<= 1) {
            s += __shfl_xor(s, m);
            ss += __shfl_xor(ss, m);
        }
        float mean = s * (1.f / 128.f);
        float var = ss * (1.f / 128.f) - mean * mean;
        float rstd = rsqrtf(var + 1e-5f);
        if (n < N) {
#pragma unroll
            for (int f = 0; f < 8; f++) {
                int col = f * 16 + lr;
                float y = (acc2[f][r] - mean) * rstd * shG[col] + shBt[col];
                h[(size_t)n * HD + col] = y;
                hh_out[(size_t)n * HD + col] = (_Float16)y;
            }
        }
    }
}

// ---------------- pooling stage 1 ----------------
__global__ __launch_bounds__(256) void k_pool1(const float* __restrict__ h,
                                               float* __restrict__ partial,
                                               int N, int RPB) {
    int bk = blockIdx.x, t = threadIdx.x;
    int j = t & 127, half = t >> 7;
    float s = 0.f;
    int rend = (bk + 1) * RPB; if (rend > N) rend = N;
    for (int r = bk * RPB + half; r < rend; r += 2) s += h[(size_t)r * HD + j];
    __shared__ float sh[256];
    sh[t] = s;
    __syncthreads();
    if (t < 128) partial[bk * HD + j] = sh[t] + sh[t + 128];
}

// ---------------- pooling stage 2 + head MLP ----------------
__global__ __launch_bounds__(128) void k_head(const float* __restrict__ partial,
                                              int nPart, int N,
                                              const float* __restrict__ hw1,
                                              const float* __restrict__ hb1,
                                              const float* __restrict__ hw2,
                                              const float* __restrict__ hb2,
                                              float* __restrict__ out) {
    __shared__ float pooled[HD];
    __shared__ float t1[HD];
    int j = threadIdx.x;
    double s = 0.0;
    for (int bk = 0; bk < nPart; bk++) s += (double)partial[bk * HD + j];
    pooled[j] = (float)(s / (double)N);
    __syncthreads();
    float acc = hb1[j];
    for (int k = 0; k < HD; k++) acc = fmaf(pooled[k], hw1[k * HD + j], acc);
    t1[j] = silu_f(acc) * hw2[j];
    __syncthreads();
    if (j < 64) t1[j] += t1[j + 64];
    __syncthreads();
    if (j < 64) {
        float v = t1[j];
#pragma unroll
        for (int o = 32; o > 0; o >>= 1) v += __shfl_xor(v, o);
        if (j == 0) out[0] = v + hb2[0];
    }
}

extern "C" void kernel_launch(void* const* d_in, const int* in_sizes, int n_in,
                              void* d_out, int out_size, void* d_ws, size_t ws_size,
                              hipStream_t stream) {
    const int* z      = (const int*)d_in[0];
    const float* pos  = (const float*)d_in[1];
    const int* ei     = (const int*)d_in[2];
    const float* lam  = (const float*)d_in[3];
    const float* aemb = (const float*)d_in[4];
    const float* lamw = (const float*)d_in[5];
    const float* lamb = (const float*)d_in[6];
    const float* ew1  = (const float*)d_in[7];
    const float* eb2  = (const float*)d_in[10];
    const float* ew2  = (const float*)d_in[9];
    const float* eb1  = (const float*)d_in[8];
    const float* nw1  = (const float*)d_in[11];
    const float* nb1  = (const float*)d_in[12];
    const float* nw2  = (const float*)d_in[13];
    const float* nb2  = (const float*)d_in[14];
    const float* lng  = (const float*)d_in[15];
    const float* lnb  = (const float*)d_in[16];
    const float* hw1  = (const float*)d_in[17];
    const float* hb1  = (const float*)d_in[18];
    const float* hw2  = (const float*)d_in[19];
    const float* hb2  = (const float*)d_in[20];

    const int N = in_sizes[0];
    const int E = in_sizes[2] / 2;

    char* ws = (char*)d_ws;
    size_t off = 0;
    auto alloc = [&](size_t bytes) { void* p = ws + off; off += (bytes + 255) & ~(size_t)255; return p; };
    float* h        = (float*)alloc((size_t)N * HD * 4);
    float* agg      = (float*)alloc((size_t)N * HD * 4);
    _Float16* hh    = (_Float16*)alloc((size_t)N * HD * 2);
    float* dist     = (float*)alloc((size_t)E * 4);
    float* lamv     = (float*)alloc(HD * 4);
    float* c1       = (float*)alloc(NLAYER * HD * 4);
    float* wd       = (float*)alloc(NLAYER * HD * 4);
    float* part     = (float*)alloc(256 * HD * 4);
    _Float16* W1te  = (_Float16*)alloc((size_t)NLAYER * 128 * 256 * 2);
    _Float16* W1tn  = (_Float16*)alloc((size_t)NLAYER * 128 * 256 * 2);
    _Float16* W2te  = (_Float16*)alloc((size_t)NLAYER * 128 * 128 * 2);
    _Float16* W2tn  = (_Float16*)alloc((size_t)NLAYER * 128 * 128 * 2);

    k_init<<<1, 256, 0, stream>>>(lam, lamw, lamb, ew1, eb1, lamv, c1);
    int prepTot = NLAYER * 128 * 256 * 2 + NLAYER * 128 * 128 * 2 + NLAYER * 128;
    k_prep<<<(prepTot + 255) / 256, 256, 0, stream>>>(ew1, ew2, nw1, nw2,
                                                      W1te, W2te, W1tn, W2tn, wd);
    int n4 = N * 32;
    k_embed<<<(n4 + 255) / 256, 256, 0, stream>>>(z, aemb, lamv, h, hh, n4);
    k_dist<<<(E + 255) / 256, 256, 0, stream>>>(pos, ei, dist, E);

    int eblocks = (E + 63) / 64;
    int nblocks = (N + 63) / 64;
    int zero4 = N * (HD / 4);
    for (int l = 0; l < NLAYER; l++) {
        k_zero<<<2048, 256, 0, stream>>>((float4*)agg, zero4);
        k_edge_mfma<<<eblocks, 256, 0, stream>>>(hh, dist, ei, E,
            W1te + (size_t)l * 128 * 256, W2te + (size_t)l * 128 * 128,
            wd + l * HD, c1 + l * HD, eb2 + l * HD, agg);
        k_node_mfma<<<nblocks, 256, 0, stream>>>(hh, agg, N,
            W1tn + (size_t)l * 128 * 256, W2tn + (size_t)l * 128 * 128,
            nb1 + l * HD, nb2 + l * HD, lng + l * HD, lnb + l * HD, h, hh);
    }
    int RPB = (N + 255) / 256;
    k_pool1<<<256, 256, 0, stream>>>(h, part, N, RPB);
    k_head<<<1, 128, 0, stream>>>(part, 256, N, hw1, hb1, hw2, hb2, (float*)d_out);
}